// Round 3
// baseline (172.603 us; speedup 1.0000x reference)
//
#include <hip/hip_runtime.h>
#include <hip/hip_fp16.h>
#include <math.h>

// 14-qubit batched statevector sim, one sample per workgroup, state in LDS as
// packed __half2 (re,im) per amp. R3: every pass uses vectorized LDS access.
//
// Pad 4 words per 32 (pidx = i + ((i>>5)<<2)): keeps 16B alignment for the
// contiguous pass (base word 36c -> 144c bytes, 144=9*16) AND spreads banks
// (4c mod 32) so all three access patterns sit at the LDS BW floor.
//   pass A (wires 0-4):  32 contiguous amps/thread, 8x ds_read_b128 (float4)
//   pass B (wires 5-9):  bit-0 paired, 64 amps/thread, 32x b64, 256 threads
//   pass C (wires 10-13):bit-0 paired, 32 amps/thread, 16x b64, 512 threads
// CNOT ring: intra-pass register renames + ext-ctrl conditional swaps; wrap
// CNOT(13,0) deferred to next layer's A pass / sign flip on z0 at readout.
// Init folded into RY-A (no read); readout folded into L3-C (no write).

#define NQ 14
#define NSTATE 16384
#define NLAYERS 4
#define NCLASSES 10
#define BLOCK 512
#define PADN (NSTATE + ((NSTATE >> 5) << 2))   // 18432 half2 words = 72 KB

__device__ __forceinline__ int pidx(int i) { return i + ((i >> 5) << 2); }
__device__ __forceinline__ __half2 f2h(float f) { return __builtin_bit_cast(__half2, f); }
__device__ __forceinline__ float   h2f(__half2 h) { return __builtin_bit_cast(float, h); }

// RX pair: a0' = c*a0 + (s,-s)*swap(a1); RY pair: a0' = c*a0 - s*a1 (real).
template<bool IS_RX>
__device__ __forceinline__ void rot_pair(__half2& a0r, __half2& a1r,
                                         const __half2 cj, const __half2 sj,
                                         const __half2 nsj)
{
  const __half2 a0 = a0r, a1 = a1r;
  if constexpr (IS_RX) {
    a0r = __hfma2(sj, __lowhigh2highlow(a1), __hmul2(cj, a0));
    a1r = __hfma2(sj, __lowhigh2highlow(a0), __hmul2(cj, a1));
  } else {
    a0r = __hfma2(nsj, a1, __hmul2(cj, a0));
    a1r = __hfma2(sj,  a0, __hmul2(cj, a1));
  }
}

template<bool IS_RX, bool INIT, bool PRE_WRAP, bool CHAIN>
__device__ __forceinline__ void pass_A(__half2* __restrict__ st,
                                       const __half2* __restrict__ cw,
                                       const __half2* __restrict__ sw)
{
  __half2 c[5], s[5];
#pragma unroll
  for (int j = 0; j < 5; ++j) { c[j] = cw[j]; s[j] = sw[j]; }
  const int ch = threadIdx.x;              // amp bits 5-13
  float4* base = (float4*)(st + 36 * ch);  // 144c bytes: 16B aligned
  __half2 a[32];
  if constexpr (INIT) {
#pragma unroll
    for (int k = 0; k < 32; ++k) a[k] = f2h(0.f);
    if (ch == 0) a[0] = __floats2half2_rn(1.f, 0.f);
  } else {
#pragma unroll
    for (int m = 0; m < 8; ++m) {
      const float4 v = base[m];
      a[4*m+0] = f2h(v.x); a[4*m+1] = f2h(v.y);
      a[4*m+2] = f2h(v.z); a[4*m+3] = f2h(v.w);
    }
  }
  if constexpr (PRE_WRAP) {               // deferred CNOT(13,0): ctrl amp bit13 = ch bit8
    if ((ch >> 8) & 1) {
#pragma unroll
      for (int k = 0; k < 32; k += 2) { __half2 t = a[k]; a[k] = a[k+1]; a[k+1] = t; }
    }
  }
#pragma unroll
  for (int j = 0; j < 5; ++j) {
    const __half2 cj = c[j], sj = s[j], nsj = __hneg2(s[j]);
#pragma unroll
    for (int k = 0; k < 32; ++k)
      if ((k & (1 << j)) == 0) rot_pair<IS_RX>(a[k], a[k | (1 << j)], cj, sj, nsj);
  }
  if constexpr (CHAIN) {                  // CNOT (0,1)(1,2)(2,3)(3,4)
#pragma unroll
    for (int j = 0; j < 4; ++j)
#pragma unroll
      for (int k = 0; k < 32; ++k)
        if ((k & (1 << j)) != 0 && (k & (2 << j)) == 0) {
          const int k2 = k | (2 << j);
          __half2 t = a[k]; a[k] = a[k2]; a[k2] = t;
        }
  }
#pragma unroll
  for (int m = 0; m < 8; ++m) {
    float4 v;
    v.x = h2f(a[4*m+0]); v.y = h2f(a[4*m+1]);
    v.z = h2f(a[4*m+2]); v.w = h2f(a[4*m+3]);
    base[m] = v;
  }
}

// pass B: only threads 0..255. Regs r = b0 | (g<<1), g = amp bits 5-9.
template<bool IS_RX, bool DO_CNOT>
__device__ __forceinline__ void pass_B(__half2* __restrict__ st,
                                       const __half2* __restrict__ cw,
                                       const __half2* __restrict__ sw)
{
  __half2 c[5], s[5];
#pragma unroll
  for (int j = 0; j < 5; ++j) { c[j] = cw[j]; s[j] = sw[j]; }
  const int ch = threadIdx.x;              // < 256: amp bits1-4 = ch&15, bits10-13 = ch>>4
  __half2* bp = st + pidx(((ch & 15) << 1) | ((ch >> 4) << 10));
  __half2 a[64];
#pragma unroll
  for (int g = 0; g < 32; ++g) {
    const float2 v = *(const float2*)(bp + 36 * g);
    a[2*g] = f2h(v.x); a[2*g+1] = f2h(v.y);
  }
#pragma unroll
  for (int j = 0; j < 5; ++j) {            // wire 5+j: partner bit (2<<j)
    const __half2 cj = c[j], sj = s[j], nsj = __hneg2(s[j]);
#pragma unroll
    for (int r = 0; r < 64; ++r)
      if ((r & (2 << j)) == 0) rot_pair<IS_RX>(a[r], a[r | (2 << j)], cj, sj, nsj);
  }
  if constexpr (DO_CNOT) {
    if ((ch >> 3) & 1) {                   // CNOT(4,5): ctrl amp bit4, tgt r bit1
#pragma unroll
      for (int r = 0; r < 64; ++r)
        if ((r & 2) == 0) { const int r1 = r | 2; __half2 t = a[r]; a[r] = a[r1]; a[r1] = t; }
    }
#pragma unroll
    for (int j = 0; j < 4; ++j)            // chain (5,6)..(8,9)
#pragma unroll
      for (int r = 0; r < 64; ++r)
        if ((r & (2 << j)) != 0 && (r & (4 << j)) == 0) {
          const int r2 = r | (4 << j);
          __half2 t = a[r]; a[r] = a[r2]; a[r2] = t;
        }
  }
#pragma unroll
  for (int g = 0; g < 32; ++g) {
    float2 v; v.x = h2f(a[2*g]); v.y = h2f(a[2*g+1]);
    *(float2*)(bp + 36 * g) = v;
  }
}

// pass C: all 512 threads. Regs r = b0 | (h<<1), h = amp bits 10-13.
template<bool IS_RX, bool DO_CNOT, bool FINAL>
__device__ __forceinline__ void pass_C(__half2* __restrict__ st,
                                       const __half2* __restrict__ cw,
                                       const __half2* __restrict__ sw,
                                       float* __restrict__ zloc)
{
  __half2 c[4], s[4];
#pragma unroll
  for (int j = 0; j < 4; ++j) { c[j] = cw[j]; s[j] = sw[j]; }
  const int ch = threadIdx.x;              // amp bits 1-9
  __half2* bp = st + pidx(ch << 1);
  __half2 a[32];
#pragma unroll
  for (int h = 0; h < 16; ++h) {
    const float2 v = *(const float2*)(bp + 1152 * h);
    a[2*h] = f2h(v.x); a[2*h+1] = f2h(v.y);
  }
#pragma unroll
  for (int j = 0; j < 4; ++j) {            // wire 10+j: partner bit (2<<j)
    const __half2 cj = c[j], sj = s[j], nsj = __hneg2(s[j]);
#pragma unroll
    for (int r = 0; r < 32; ++r)
      if ((r & (2 << j)) == 0) rot_pair<IS_RX>(a[r], a[r | (2 << j)], cj, sj, nsj);
  }
  if constexpr (DO_CNOT) {
    if ((ch >> 8) & 1) {                   // CNOT(9,10): ctrl amp bit9, tgt r bit1
#pragma unroll
      for (int r = 0; r < 32; ++r)
        if ((r & 2) == 0) { const int r1 = r | 2; __half2 t = a[r]; a[r] = a[r1]; a[r1] = t; }
    }
#pragma unroll
    for (int j = 0; j < 3; ++j)            // chain (10,11)(11,12)(12,13)
#pragma unroll
      for (int r = 0; r < 32; ++r)
        if ((r & (2 << j)) != 0 && (r & (4 << j)) == 0) {
          const int r2 = r | (4 << j);
          __half2 t = a[r]; a[r] = a[r2]; a[r2] = t;
        }
  }
  if constexpr (FINAL) {
    // r: b0 = r&1 (wire 0), bit13 = r bit4; ch bits 0-8 = wires 1-9.
    float ssum = 0.f, sx0 = 0.f, sb[4] = {0.f, 0.f, 0.f, 0.f};
#pragma unroll
    for (int r = 0; r < 32; ++r) {
      const float2 v = __half22float2(a[r]);
      const float p = fmaf(v.x, v.x, v.y * v.y);
      ssum += p;
      if ((r ^ (r >> 4)) & 1) sx0 += p;    // b0 XOR bit13 (pending wrap CNOT)
      if (r & 2)  sb[0] += p;
      if (r & 4)  sb[1] += p;
      if (r & 8)  sb[2] += p;
      if (r & 16) sb[3] += p;
    }
    zloc[0] += ssum - 2.f * sx0;
#pragma unroll
    for (int j = 0; j < 4; ++j) zloc[10 + j] += ssum - 2.f * sb[j];
#pragma unroll
    for (int w = 1; w <= 9; ++w) zloc[w] += ((ch >> (w - 1)) & 1) ? -ssum : ssum;
  } else {
#pragma unroll
    for (int h = 0; h < 16; ++h) {
      float2 v; v.x = h2f(a[2*h]); v.y = h2f(a[2*h+1]);
      *(float2*)(bp + 1152 * h) = v;
    }
  }
}

__global__ __launch_bounds__(BLOCK) void qsim_kernel(
    const float* __restrict__ x, const float* __restrict__ qp,
    const float* __restrict__ fcw, const float* __restrict__ fcb,
    float* __restrict__ out)
{
  extern __shared__ unsigned char smem[];
  __half2* st  = (__half2*)smem;
  __half2* ryc = st + PADN;                 // 14
  __half2* rys = ryc + NQ;                  // 14
  __half2* rxc = rys + NQ;                  // 56
  __half2* rxs = rxc + NLAYERS * NQ;        // 56
  float*   zbuf  = (float*)(rxs + NLAYERS * NQ);  // 14
  float*   zpart = zbuf + NQ;               // 8*14

  const int b   = blockIdx.x;
  const int tid = threadIdx.x;

  if (tid < NQ) {
    float sv, cv;
    sincosf(0.5f * x[b * NQ + tid], &sv, &cv);
    ryc[tid] = __floats2half2_rn(cv, cv);
    rys[tid] = __floats2half2_rn(sv, sv);
  } else if (tid >= 64 && tid < 64 + NLAYERS * NQ) {
    const int k = tid - 64;
    float sv, cv;
    sincosf(0.5f * qp[k], &sv, &cv);
    rxc[k] = __floats2half2_rn(cv, cv);
    rxs[k] = __floats2half2_rn(sv, -sv);    // (s,-s) for the RX swap form
  }
  __syncthreads();

  // RY embedding (init folded into pass A)
  pass_A<false, true, false, false>(st, ryc, rys);            __syncthreads();
  if (tid < 256) pass_B<false, false>(st, ryc + 5, rys + 5);  __syncthreads();
  pass_C<false, false, false>(st, ryc + 10, rys + 10, nullptr); __syncthreads();

  float zloc[NQ];
#pragma unroll
  for (int w = 0; w < NQ; ++w) zloc[w] = 0.f;

#pragma unroll
  for (int l = 0; l < NLAYERS; ++l) {
    const __half2* lc = rxc + l * NQ;
    const __half2* ls = rxs + l * NQ;
    if (l == 0) pass_A<true, false, false, true>(st, lc, ls);
    else        pass_A<true, false, true,  true>(st, lc, ls);   // + deferred CNOT(13,0)
    __syncthreads();
    if (tid < 256) pass_B<true, true>(st, lc + 5, ls + 5);
    __syncthreads();
    if (l < NLAYERS - 1) {
      pass_C<true, true, false>(st, lc + 10, ls + 10, nullptr);
      __syncthreads();
    } else {
      pass_C<true, true, true>(st, lc + 10, ls + 10, zloc);     // fused readout
    }
  }

  // wave reduce (64 lanes), then per-wave partials in LDS
#pragma unroll
  for (int w = 0; w < NQ; ++w) {
#pragma unroll
    for (int off = 32; off > 0; off >>= 1)
      zloc[w] += __shfl_down(zloc[w], off, 64);
  }
  const int wave = tid >> 6, lane = tid & 63;
  if (lane == 0) {
#pragma unroll
    for (int w = 0; w < NQ; ++w) zpart[wave * NQ + w] = zloc[w];
  }
  __syncthreads();
  if (tid < NQ) {
    float acc = 0.f;
#pragma unroll
    for (int v = 0; v < BLOCK / 64; ++v) acc += zpart[v * NQ + tid];
    zbuf[tid] = acc;
  }
  __syncthreads();

  if (tid < NCLASSES) {
    float acc = fcb[tid];
#pragma unroll
    for (int w = 0; w < NQ; ++w) acc = fmaf(zbuf[w], fcw[tid * NQ + w], acc);
    out[b * NCLASSES + tid] = acc;
  }
}

extern "C" void kernel_launch(void* const* d_in, const int* in_sizes, int n_in,
                              void* d_out, int out_size, void* d_ws, size_t ws_size,
                              hipStream_t stream) {
  const float* x   = (const float*)d_in[0];
  const float* qp  = (const float*)d_in[1];
  const float* fcw = (const float*)d_in[2];
  const float* fcb = (const float*)d_in[3];
  float* out = (float*)d_out;
  const int B = in_sizes[0] / NQ;

  const size_t shmem = (size_t)PADN * sizeof(__half2)
                     + (size_t)(2 * NQ + 2 * NLAYERS * NQ) * sizeof(__half2)
                     + (size_t)(NQ + (BLOCK / 64) * NQ) * sizeof(float);
  // ~74.8 KB dynamic LDS > 64 KB default cap: raise the limit (capture-safe).
  (void)hipFuncSetAttribute((const void*)qsim_kernel,
                            hipFuncAttributeMaxDynamicSharedMemorySize, (int)shmem);
  qsim_kernel<<<B, BLOCK, shmem, stream>>>(x, qp, fcw, fcb, out);
}

// Round 4
// 161.595 us; speedup vs baseline: 1.0681x; 1.0681x over previous
//
#include <hip/hip_runtime.h>
#include <hip/hip_fp16.h>
#include <math.h>

// 14-qubit batched statevector sim, one sample/workgroup, state in LDS.
// R4 layout: word[2P]   = (re[amp 2P], re[amp 2P+1])   (packed __half2)
//            word[2P+1] = (im[amp 2P], im[amp 2P+1])
// -> all gate math on wires>=1 is pure vertical v_pk_fma_f16 (2 ops/amp, no
// swaps); wire 0 lives inside the vector (3 ops/amp, only in pass A).
// Pass groups (all 512 threads, 16 pairs each -> no wave imbalance):
//   A: wires 0-4   (wire0 in-vector, wires1-4 = reg bits 0-3)
//   B: wires 5-8 = reg bits 0-3; wire 9 = lane bit 0 via __shfl_xor(1)
//   C: wires 10-13 = reg bits 0-3
// CNOT ring: chain CNOTs = compile-time store-index map (free); (4,5)/(9,10)
// = uniform masked reg swaps; (0,1) = high-half blend; (8,9) = lane shfl on
// k-bit3 regs; (13,0) deferred to next A pass / readout sign flip on z0.
// Pad 2 words per 64 (pidx = i + ((i>>6)<<1)): total 16896 words = 67584 B —
// EXACTLY R2's footprint (2 blocks/CU confirmed there; 74.8 KB lost it in R3).
// All bases even -> 8B-aligned b64 access at the bank-BW floor.

#define NQ 14
#define NLAYERS 4
#define NCLASSES 10
#define BLOCK 512
#define NWORDS 16384
#define PADW (NWORDS + ((NWORDS >> 6) << 1))   // 16896 half2 = 67584 B

__device__ __forceinline__ __half2 bch(unsigned u) { return __builtin_bit_cast(__half2, u); }
__device__ __forceinline__ unsigned hcb(__half2 v) { return __builtin_bit_cast(unsigned, v); }
__device__ __forceinline__ __half2 hswap(__half2 v) { return __lowhigh2highlow(v); }
__device__ __forceinline__ __half2 shfl1(__half2 v) {
  return __builtin_bit_cast(__half2, __shfl_xor(__builtin_bit_cast(float, v), 1, 64));
}
// store-index map for chain CNOTs (ctrl k-bit j -> tgt k-bit j+1, j=0,1,2):
// S'[p] = S[c01(c12(c23(p)))]
__host__ __device__ constexpr int chainmap(int k) {
  int p = k ^ (((k >> 2) & 1) << 3);
  p ^= (((p >> 1) & 1) << 2);
  p ^= ((p & 1) << 1);
  return p;
}

// reg-pair rotation on (k0,k1): RX: re' = c*re + s*im_partner; im' = c*im - s*re_partner
//                               RY: a0' = c*a0 - s*a1 ; a1' = s*a0 + c*a1 (re,im alike)
template<bool IS_RX>
__device__ __forceinline__ void rot_regs(__half2* rev, __half2* imv, int k, int k1,
                                         __half2 c2, __half2 s2, __half2 ns2) {
  const __half2 r0 = rev[k], m0 = imv[k], r1 = rev[k1], m1 = imv[k1];
  if constexpr (IS_RX) {
    rev[k]  = __hfma2(s2, m1, __hmul2(c2, r0));
    imv[k]  = __hfma2(ns2, r1, __hmul2(c2, m0));
    rev[k1] = __hfma2(s2, m0, __hmul2(c2, r1));
    imv[k1] = __hfma2(ns2, r0, __hmul2(c2, m1));
  } else {
    rev[k]  = __hfma2(ns2, r1, __hmul2(c2, r0));
    imv[k]  = __hfma2(ns2, m1, __hmul2(c2, m0));
    rev[k1] = __hfma2(s2, r0, __hmul2(c2, r1));
    imv[k1] = __hfma2(s2, m0, __hmul2(c2, m1));
  }
}

template<bool IS_RX, bool INIT, bool WRAP, bool CHAIN>
__device__ __forceinline__ void pass_A(__half2* __restrict__ st,
                                       const __half2* __restrict__ cw,
                                       const __half2* __restrict__ sw) {
  const int ch = threadIdx.x;                  // pair bits 4-12
  __half2* bp = st + 32 * ch + 2 * (ch >> 1);  // padded base (even word)
  __half2 rev[16], imv[16];
  if constexpr (INIT) {
#pragma unroll
    for (int k = 0; k < 16; ++k) { rev[k] = bch(0u); imv[k] = bch(0u); }
    if (ch == 0) rev[0] = __floats2half2_rn(1.f, 0.f);
  } else {
#pragma unroll
    for (int k = 0; k < 16; ++k) {
      const float2 v = *(const float2*)(bp + 2 * k);
      rev[k] = __builtin_bit_cast(__half2, v.x);
      imv[k] = __builtin_bit_cast(__half2, v.y);
    }
  }
  if constexpr (WRAP) {                        // deferred CNOT(13,0): ctrl = ch bit8
    if ((ch >> 8) & 1) {
#pragma unroll
      for (int k = 0; k < 16; ++k) { rev[k] = hswap(rev[k]); imv[k] = hswap(imv[k]); }
    }
  }
  // wire 0 (intra-vector)
  {
    const __half2 c2 = cw[0], s2 = sw[0];
    if constexpr (IS_RX) {
      const __half2 ns2 = __hneg2(s2);
#pragma unroll
      for (int k = 0; k < 16; ++k) {
        const __half2 orv = rev[k], omv = imv[k];
        rev[k] = __hfma2(s2, hswap(omv), __hmul2(c2, orv));
        imv[k] = __hfma2(ns2, hswap(orv), __hmul2(c2, omv));
      }
    } else {
      const __half2 mix = bch(hcb(s2) ^ 0x8000u);   // (-s, s)
#pragma unroll
      for (int k = 0; k < 16; ++k) {
        rev[k] = __hfma2(mix, hswap(rev[k]), __hmul2(c2, rev[k]));
        imv[k] = __hfma2(mix, hswap(imv[k]), __hmul2(c2, imv[k]));
      }
    }
  }
  // wires 1-4 = reg bits 0-3
#pragma unroll
  for (int j = 0; j < 4; ++j) {
    const __half2 c2 = cw[1 + j], s2 = sw[1 + j], ns2 = __hneg2(sw[1 + j]);
#pragma unroll
    for (int k = 0; k < 16; ++k)
      if ((k & (1 << j)) == 0) rot_regs<IS_RX>(rev, imv, k, k | (1 << j), c2, s2, ns2);
  }
  if constexpr (CHAIN) {
    // CNOT(0,1): ctrl in-vector (high half), tgt reg bit0 -> blend high halves
#pragma unroll
    for (int k = 0; k < 16; k += 2) {
      const unsigned ra = hcb(rev[k]), rb = hcb(rev[k + 1]);
      rev[k]     = bch((ra & 0xFFFFu) | (rb & 0xFFFF0000u));
      rev[k + 1] = bch((rb & 0xFFFFu) | (ra & 0xFFFF0000u));
      const unsigned ma = hcb(imv[k]), mb = hcb(imv[k + 1]);
      imv[k]     = bch((ma & 0xFFFFu) | (mb & 0xFFFF0000u));
      imv[k + 1] = bch((mb & 0xFFFFu) | (ma & 0xFFFF0000u));
    }
  }
#pragma unroll
  for (int k = 0; k < 16; ++k) {               // chain CNOTs (1,2)(2,3)(3,4) = index map
    const int src = CHAIN ? chainmap(k) : k;
    float2 v;
    v.x = __builtin_bit_cast(float, rev[src]);
    v.y = __builtin_bit_cast(float, imv[src]);
    *(float2*)(bp + 2 * k) = v;
  }
}

template<bool IS_RX, bool CNOTS>
__device__ __forceinline__ void pass_B(__half2* __restrict__ st,
                                       const __half2* __restrict__ cw,
                                       const __half2* __restrict__ sw) {
  const int ch = threadIdx.x;
  // thread bits: ch0=pair bit8 (wire9, lane partner), ch1-4=pair bits 0-3, ch5-8=pair bits 9-12
  const int u = ((ch >> 1) & 15) | ((ch & 1) << 8) | ((ch >> 5) << 9);
  __half2* bp = st + 2 * u + 2 * (u >> 5);
  __half2 rev[16], imv[16];
#pragma unroll
  for (int k = 0; k < 16; ++k) {
    const float2 v = *(const float2*)(bp + 32 * k + 2 * (k >> 1));
    rev[k] = __builtin_bit_cast(__half2, v.x);
    imv[k] = __builtin_bit_cast(__half2, v.y);
  }
  // wires 5-8 = reg bits 0-3
#pragma unroll
  for (int j = 0; j < 4; ++j) {
    const __half2 c2 = cw[j], s2 = sw[j], ns2 = __hneg2(sw[j]);
#pragma unroll
    for (int k = 0; k < 16; ++k)
      if ((k & (1 << j)) == 0) rot_regs<IS_RX>(rev, imv, k, k | (1 << j), c2, s2, ns2);
  }
  // wire 9: partner = lane^1
  {
    const __half2 c2 = cw[4], s2 = sw[4];
    if constexpr (IS_RX) {                     // symmetric: a' = c*a - i s*partner
      const __half2 ns2 = __hneg2(s2);
#pragma unroll
      for (int k = 0; k < 16; ++k) {
        const __half2 pr = shfl1(rev[k]), pm = shfl1(imv[k]);
        rev[k] = __hfma2(s2, pm, __hmul2(c2, rev[k]));
        imv[k] = __hfma2(ns2, pr, __hmul2(c2, imv[k]));
      }
    } else {                                   // RY: side-dependent sign
      const __half2 sg = (ch & 1) ? s2 : __hneg2(s2);
#pragma unroll
      for (int k = 0; k < 16; ++k) {
        const __half2 pr = shfl1(rev[k]), pm = shfl1(imv[k]);
        rev[k] = __hfma2(sg, pr, __hmul2(c2, rev[k]));
        imv[k] = __hfma2(sg, pm, __hmul2(c2, imv[k]));
      }
    }
  }
  if constexpr (CNOTS) {
    if ((ch >> 4) & 1) {                       // CNOT(4,5): ctrl pair bit3, tgt reg bit0
#pragma unroll
      for (int k = 0; k < 16; k += 2) {
        __half2 t = rev[k]; rev[k] = rev[k + 1]; rev[k + 1] = t;
        t = imv[k]; imv[k] = imv[k + 1]; imv[k + 1] = t;
      }
    }
  }
#pragma unroll
  for (int k = 0; k < 16; ++k) {               // chain (5,6)(6,7)(7,8) map + CNOT(8,9) shfl
    const int src = CNOTS ? chainmap(k) : k;
    __half2 vr = rev[src], vm = imv[src];
    if constexpr (CNOTS) {
      if (k & 8) { vr = shfl1(vr); vm = shfl1(vm); }   // CNOT(8,9): ctrl k bit3, tgt lane bit
    }
    float2 v;
    v.x = __builtin_bit_cast(float, vr);
    v.y = __builtin_bit_cast(float, vm);
    *(float2*)(bp + 32 * k + 2 * (k >> 1)) = v;
  }
}

template<bool IS_RX, bool CNOTS, bool FINAL>
__device__ __forceinline__ void pass_C(__half2* __restrict__ st,
                                       const __half2* __restrict__ cw,
                                       const __half2* __restrict__ sw,
                                       float* __restrict__ zloc) {
  const int ch = threadIdx.x;                  // pair bits 0-8 (wires 1-9)
  __half2* bp = st + 2 * ch + 2 * (ch >> 5);
  __half2 rev[16], imv[16];
#pragma unroll
  for (int k = 0; k < 16; ++k) {
    const float2 v = *(const float2*)(bp + 1056 * k);
    rev[k] = __builtin_bit_cast(__half2, v.x);
    imv[k] = __builtin_bit_cast(__half2, v.y);
  }
  // wires 10-13 = reg bits 0-3
#pragma unroll
  for (int j = 0; j < 4; ++j) {
    const __half2 c2 = cw[j], s2 = sw[j], ns2 = __hneg2(sw[j]);
#pragma unroll
    for (int k = 0; k < 16; ++k)
      if ((k & (1 << j)) == 0) rot_regs<IS_RX>(rev, imv, k, k | (1 << j), c2, s2, ns2);
  }
  if constexpr (CNOTS) {
    if ((ch >> 8) & 1) {                       // CNOT(9,10): ctrl pair bit8, tgt reg bit0
#pragma unroll
      for (int k = 0; k < 16; k += 2) {
        __half2 t = rev[k]; rev[k] = rev[k + 1]; rev[k + 1] = t;
        t = imv[k]; imv[k] = imv[k + 1]; imv[k + 1] = t;
      }
    }
  }
  if constexpr (FINAL) {
    // pending CNOT(13,0): z0 per amp = (-1)^(bit0 ^ bit13)*p ; bit13 = k bit3
    float ssum = 0.f, z0 = 0.f, zA = 0.f, zB = 0.f, zC = 0.f, zD = 0.f;
#pragma unroll
    for (int k = 0; k < 16; ++k) {
      const int src = chainmap(k);             // chain (10,11)(11,12)(12,13)
      const float2 r = __half22float2(rev[src]);
      const float2 m = __half22float2(imv[src]);
      const float p0 = fmaf(r.x, r.x, m.x * m.x);
      const float p1 = fmaf(r.y, r.y, m.y * m.y);
      const float ps = p0 + p1, d = p0 - p1;
      ssum += ps;
      z0 += (k & 8) ? -d : d;
      zA += (k & 1) ? -ps : ps;
      zB += (k & 2) ? -ps : ps;
      zC += (k & 4) ? -ps : ps;
      zD += (k & 8) ? -ps : ps;
    }
    zloc[0] = z0; zloc[10] = zA; zloc[11] = zB; zloc[12] = zC; zloc[13] = zD;
#pragma unroll
    for (int w = 1; w <= 9; ++w) zloc[w] = ((ch >> (w - 1)) & 1) ? -ssum : ssum;
  } else {
#pragma unroll
    for (int k = 0; k < 16; ++k) {
      const int src = CNOTS ? chainmap(k) : k;
      float2 v;
      v.x = __builtin_bit_cast(float, rev[src]);
      v.y = __builtin_bit_cast(float, imv[src]);
      *(float2*)(bp + 1056 * k) = v;
    }
  }
}

__global__ __launch_bounds__(BLOCK, 4) void qsim_kernel(
    const float* __restrict__ x, const float* __restrict__ qp,
    const float* __restrict__ fcw, const float* __restrict__ fcb,
    float* __restrict__ out) {
  extern __shared__ unsigned char smem[];
  __half2* st  = (__half2*)smem;
  __half2* ryc = st + PADW;                 // 14
  __half2* rys = ryc + NQ;                  // 14
  __half2* rxc = rys + NQ;                  // 56
  __half2* rxs = rxc + NLAYERS * NQ;        // 56
  float* zbuf  = (float*)(rxs + NLAYERS * NQ);   // 14
  float* zpart = zbuf + NQ;                 // 8*14

  const int b = blockIdx.x;
  const int tid = threadIdx.x;

  if (tid < NQ) {
    float sv, cv;
    sincosf(0.5f * x[b * NQ + tid], &sv, &cv);
    ryc[tid] = __floats2half2_rn(cv, cv);
    rys[tid] = __floats2half2_rn(sv, sv);
  } else if (tid >= 64 && tid < 64 + NLAYERS * NQ) {
    const int k = tid - 64;
    float sv, cv;
    sincosf(0.5f * qp[k], &sv, &cv);
    rxc[k] = __floats2half2_rn(cv, cv);
    rxs[k] = __floats2half2_rn(sv, sv);
  }
  __syncthreads();

  // RY embedding (init folded into pass A)
  pass_A<false, true, false, false>(st, ryc, rys);             __syncthreads();
  pass_B<false, false>(st, ryc + 5, rys + 5);                  __syncthreads();
  pass_C<false, false, false>(st, ryc + 10, rys + 10, nullptr); __syncthreads();

  float zloc[NQ];
#pragma unroll
  for (int l = 0; l < NLAYERS; ++l) {
    const __half2* lc = rxc + l * NQ;
    const __half2* ls = rxs + l * NQ;
    if (l == 0) pass_A<true, false, false, true>(st, lc, ls);
    else        pass_A<true, false, true, true>(st, lc, ls);   // + deferred CNOT(13,0)
    __syncthreads();
    pass_B<true, true>(st, lc + 5, ls + 5);                    __syncthreads();
    if (l < NLAYERS - 1) {
      pass_C<true, true, false>(st, lc + 10, ls + 10, nullptr); __syncthreads();
    } else {
      pass_C<true, true, true>(st, lc + 10, ls + 10, zloc);    // fused readout
    }
  }

  // wave reduce (64 lanes), then per-wave partials in LDS
#pragma unroll
  for (int w = 0; w < NQ; ++w) {
#pragma unroll
    for (int off = 32; off > 0; off >>= 1)
      zloc[w] += __shfl_down(zloc[w], off, 64);
  }
  const int wave = tid >> 6, lane = tid & 63;
  if (lane == 0) {
#pragma unroll
    for (int w = 0; w < NQ; ++w) zpart[wave * NQ + w] = zloc[w];
  }
  __syncthreads();
  if (tid < NQ) {
    float acc = 0.f;
#pragma unroll
    for (int v = 0; v < BLOCK / 64; ++v) acc += zpart[v * NQ + tid];
    zbuf[tid] = acc;
  }
  __syncthreads();

  if (tid < NCLASSES) {
    float acc = fcb[tid];
#pragma unroll
    for (int w = 0; w < NQ; ++w) acc = fmaf(zbuf[w], fcw[tid * NQ + w], acc);
    out[b * NCLASSES + tid] = acc;
  }
}

extern "C" void kernel_launch(void* const* d_in, const int* in_sizes, int n_in,
                              void* d_out, int out_size, void* d_ws, size_t ws_size,
                              hipStream_t stream) {
  const float* x   = (const float*)d_in[0];
  const float* qp  = (const float*)d_in[1];
  const float* fcw = (const float*)d_in[2];
  const float* fcb = (const float*)d_in[3];
  float* out = (float*)d_out;
  const int B = in_sizes[0] / NQ;

  const size_t shmem = (size_t)PADW * sizeof(__half2)
                     + (size_t)(2 * NQ + 2 * NLAYERS * NQ) * sizeof(__half2)
                     + (size_t)(NQ + (BLOCK / 64) * NQ) * sizeof(float);
  // ~68.6 KB dynamic LDS > 64 KB default cap: raise the limit (capture-safe).
  (void)hipFuncSetAttribute((const void*)qsim_kernel,
                            hipFuncAttributeMaxDynamicSharedMemorySize, (int)shmem);
  qsim_kernel<<<B, BLOCK, shmem, stream>>>(x, qp, fcw, fcb, out);
}

// Round 6
// 146.113 us; speedup vs baseline: 1.1813x; 1.1060x over previous
//
#include <hip/hip_runtime.h>
#include <hip/hip_fp16.h>
#include <math.h>

// 14-qubit batched statevector sim. R6 = R5 MFMA engine + checkerboard parity
// FIX: parity(finv(n)) telescopes to the TOP bit of n (bit4 for the 5-wire
// chain, bit3 for the 4-wire chain), NOT popc(n). R5 used popc -> dominant
// real entries routed to the imag plane on half the columns -> amp *= i (pure
// phase, zeroth-order invisible) -> first-order-in-sin leak = the 1.6e-2 fail.
//
// State: separate re/im _Float16 planes (16384 each, 64 KB), XOR-swizzled
// phys = idx ^ (((idx>>9)&7)<<3)  -> b128 A-reads and b64 C-writes both at
// LDS bank floors, no padding bytes.
// Each pass: S' = S * U^T as complex GEMM with v_mfma_f32_16x16x32_f16.
//   A-frag: A[m=lane&15][k=8*(lane>>4)+j]; B-frag B[k][n=lane&15] from the
//   U-plane; U entries are pure-real or pure-imag (RX products): ONE signed
//   plane + checkerboard split. C/D: col=lane&15, row=4*(lane>>4)+reg.
// Store rotates the index (5,5,4 bits/layer) so every pass's wires are low.
// Cross-group CNOT(4,5)/(9,10): wave-uniform B-address flip n^31 / n^15
// (finv(n^31)=finv(n)^1). Wrap CNOT(13,0): reg-pair swap at pass-C store
// (ctrl = cc bit3). Embed RYs + layer-1 pass-A are closed-form rank-1 init.
// In-place permutation hazard: compute-all -> barrier -> write-all per pass.
// LDS: 65536 + 2048 + 448 + 112 = 68144 B (<= 68648 = known 2-blocks/CU).

#define NQ 14
#define NLAYERS 4
#define NCLASSES 10
#define BLOCK 512

typedef _Float16 f16;
typedef _Float16 f16x8 __attribute__((ext_vector_type(8)));
typedef _Float16 f16x4 __attribute__((ext_vector_type(4)));
typedef float f32x4 __attribute__((ext_vector_type(4)));
typedef unsigned int u32;
typedef u32 u32x4 __attribute__((ext_vector_type(4)));

__device__ __forceinline__ f32x4 mf(f16x8 a, f16x8 b, f32x4 c) {
  return __builtin_amdgcn_mfma_f32_16x16x32_f16(a, b, c, 0, 0, 0);
}

// inverse of the 4-CNOT chain (b0->b1->...->b4) basis map
__device__ __forceinline__ int finv5(int n) {
  n ^= ((n >> 3) & 1) << 4;
  n ^= ((n >> 2) & 1) << 3;
  n ^= ((n >> 1) & 1) << 2;
  n ^= (n & 1) << 1;
  return n;
}
// inverse of the 3-CNOT chain on 4 bits
__device__ __forceinline__ int finv3(int n) {
  n ^= ((n >> 2) & 1) << 3;
  n ^= ((n >> 1) & 1) << 2;
  n ^= (n & 1) << 1;
  return n;
}

// split combined U plane fragment into re/im by checkerboard parity.
// element j is REAL iff parity(j)==s, where s = parity(finv(n)) ^ parity(8q)
// and parity(finv(n)) = TOP BIT of n (telescoping XOR).
__device__ __forceinline__ void splitB(f16x8 b, int s, f16x8& br, f16x8& bi) {
  u32x4 u = __builtin_bit_cast(u32x4, b);
  const u32 m0 = s ? 0xFFFF0000u : 0x0000FFFFu;   // (j0,j1) and (j6,j7)
  const u32 m1 = s ? 0x0000FFFFu : 0xFFFF0000u;   // (j2,j3) and (j4,j5)
  u32x4 r;
  r[0] = u[0] & m0; r[1] = u[1] & m1; r[2] = u[2] & m1; r[3] = u[3] & m0;
  u32x4 ii;
  ii[0] = u[0] ^ r[0]; ii[1] = u[1] ^ r[1]; ii[2] = u[2] ^ r[2]; ii[3] = u[3] ^ r[3];
  br = __builtin_bit_cast(f16x8, r);
  bi = __builtin_bit_cast(f16x8, ii);
}

// Build 32x32 U-plane: RX(angles[base..base+4]) on bits0-4 then chain CNOTs.
__device__ __forceinline__ void build32(f16* Bc, const float* qc, const float* qs,
                                        int base, int tid) {
  const float c0 = qc[base], c1 = qc[base+1], c2 = qc[base+2], c3 = qc[base+3], c4 = qc[base+4];
  const float s0 = qs[base], s1 = qs[base+1], s2 = qs[base+2], s3 = qs[base+3], s4 = qs[base+4];
#pragma unroll
  for (int e = tid; e < 1024; e += BLOCK) {
    const int n = e >> 5, k = e & 31;
    const int d = finv5(n) ^ k;
    float mag = ((d & 1) ? s0 : c0) * ((d & 2) ? s1 : c1);
    mag *= ((d & 4) ? s2 : c2) * ((d & 8) ? s3 : c3);
    mag *= ((d & 16) ? s4 : c4);
    const int t = __popc(d) & 3;          // phase (-i)^t
    Bc[n * 32 + k] = (f16)((t == 1 || t == 2) ? -mag : mag);
  }
}

// Pass-C plane: 16 cols x 32 k rows (k>=16 zero-padded), RX on bits0-3 + 3-chain.
__device__ __forceinline__ void buildC(f16* Bc, const float* qc, const float* qs,
                                       int base, int tid) {
  const float c0 = qc[base], c1 = qc[base+1], c2 = qc[base+2], c3 = qc[base+3];
  const float s0 = qs[base], s1 = qs[base+1], s2 = qs[base+2], s3 = qs[base+3];
  if (tid < 512) {
    const int n = tid >> 5, k = tid & 31;
    float v = 0.f;
    if (k < 16) {
      const int d = finv3(n) ^ k;
      float mag = ((d & 1) ? s0 : c0) * ((d & 2) ? s1 : c1);
      mag *= ((d & 4) ? s2 : c2) * ((d & 8) ? s3 : c3);
      const int t = __popc(d) & 3;
      v = (t == 1 || t == 2) ? -mag : mag;
    }
    Bc[n * 32 + k] = (f16)v;
  }
}

// 5-wire GEMM pass (K=32). Reads whole state, barrier, writes rotated.
template<bool CTRL>
__device__ __forceinline__ void pass32(f16* __restrict__ reP, f16* __restrict__ imP,
                                       const f16* __restrict__ Bc, int tid) {
  const int lane = tid & 63, wave = tid >> 6;
  const int q = lane >> 4, cc = lane & 15;
  int n0 = cc, n1 = cc | 16;
  if (CTRL && wave >= 4) { n0 ^= 31; n1 ^= 31; }   // ext-ctrl CNOT variant
  const int pq = (0x6 >> q) & 1;
  f16x8 br0, bi0, br1, bi1;
  {
    const f16x8 b0 = *(const f16x8*)(Bc + n0 * 32 + 8 * q);
    const f16x8 b1 = *(const f16x8*)(Bc + n1 * 32 + 8 * q);
    splitB(b0, ((n0 >> 4) ^ pq) & 1, br0, bi0);   // FIX: parity(finv5(n)) = bit4(n)
    splitB(b1, ((n1 >> 4) ^ pq) & 1, br1, bi1);
  }
  f16x4 outR[8], outI[8];
#pragma unroll
  for (int i = 0; i < 4; ++i) {
    const int mt = wave * 4 + i;
    const int pA = ((mt * 16 + cc) * 32 + 8 * q) ^ ((mt & 7) << 3);
    const f16x8 Ar = *(const f16x8*)(reP + pA);
    const f16x8 Ai = *(const f16x8*)(imP + pA);
    const f16x8 nAi = -Ai;
#pragma unroll
    for (int nt = 0; nt < 2; ++nt) {
      const f16x8 br = nt ? br1 : br0;
      const f16x8 bi = nt ? bi1 : bi0;
      f32x4 aR = {0.f, 0.f, 0.f, 0.f}, aI = {0.f, 0.f, 0.f, 0.f};
      aR = mf(Ar, br, aR); aR = mf(nAi, bi, aR);
      aI = mf(Ar, bi, aI); aI = mf(Ai, br, aI);
      outR[i * 2 + nt] = __builtin_convertvector(aR, f16x4);
      outI[i * 2 + nt] = __builtin_convertvector(aI, f16x4);
    }
  }
  __syncthreads();   // all reads done before in-place permuted writes
#pragma unroll
  for (int i = 0; i < 4; ++i) {
#pragma unroll
    for (int nt = 0; nt < 2; ++nt) {
      const int n5 = nt * 16 + cc;
      const int rr = (wave * 4 + i) * 16 + 4 * q;
      const int pS = (rr | (n5 << 9)) ^ ((n5 & 7) << 3);
      *(f16x4*)(reP + pS) = outR[i * 2 + nt];
      *(f16x4*)(imP + pS) = outI[i * 2 + nt];
    }
  }
}

// 4-wire pass C (K padded to 32). Always has ext-ctrl (9,10).
// Wrap CNOT(13,0) = reg-pair swap at store (ctrl = cc bit3). FINAL fuses readout.
template<bool FINAL>
__device__ __forceinline__ void passC(f16* __restrict__ reP, f16* __restrict__ imP,
                                      const f16* __restrict__ Bc, int tid,
                                      float* __restrict__ zloc) {
  const int lane = tid & 63, wave = tid >> 6;
  const int q = lane >> 4, cc = lane & 15;
  int n0 = cc;
  if (wave >= 4) n0 ^= 15;
  const int pq = (0x6 >> q) & 1;
  f16x8 br, bi;
  {
    const f16x8 b = *(const f16x8*)(Bc + n0 * 32 + 8 * q);
    splitB(b, ((n0 >> 3) ^ pq) & 1, br, bi);      // FIX: parity(finv3(n)) = bit3(n)
  }
  f16x4 outR[8], outI[8];
#pragma unroll
  for (int i = 0; i < 8; ++i) {
    const int mt = wave * 8 + i;
    const int pA = ((mt * 16 + cc) * 16 + 8 * (q & 1)) ^ (((mt >> 1) & 7) << 3);
    const f16x8 Ar = *(const f16x8*)(reP + pA);
    const f16x8 Ai = *(const f16x8*)(imP + pA);
    const f16x8 nAi = -Ai;
    f32x4 aR = {0.f, 0.f, 0.f, 0.f}, aI = {0.f, 0.f, 0.f, 0.f};
    aR = mf(Ar, br, aR); aR = mf(nAi, bi, aR);
    aI = mf(Ar, bi, aI); aI = mf(Ai, br, aI);
    if constexpr (FINAL) {
      float p0 = aR[0]*aR[0] + aI[0]*aI[0];
      float p1 = aR[1]*aR[1] + aI[1]*aI[1];
      float p2 = aR[2]*aR[2] + aI[2]*aI[2];
      float p3 = aR[3]*aR[3] + aI[3]*aI[3];
      if (cc & 8) { float t = p0; p0 = p1; p1 = t; t = p2; p2 = p3; p3 = t; }
      const float ps = p0 + p1 + p2 + p3;
      zloc[0] += (p0 - p1) + (p2 - p3);
      zloc[1] += (p0 + p1) - (p2 + p3);
      zloc[2] += (q & 1) ? -ps : ps;
      zloc[3] += (q & 2) ? -ps : ps;
#pragma unroll
      for (int w = 0; w < 6; ++w) zloc[4 + w] += ((mt >> w) & 1) ? -ps : ps;
#pragma unroll
      for (int w = 0; w < 4; ++w) zloc[10 + w] += ((cc >> w) & 1) ? -ps : ps;
    } else {
      if (cc & 8) {   // pending CNOT(13,0): swap rows differing in new bit0
        f32x4 tR = aR, tI = aI;
        aR[0] = tR[1]; aR[1] = tR[0]; aR[2] = tR[3]; aR[3] = tR[2];
        aI[0] = tI[1]; aI[1] = tI[0]; aI[2] = tI[3]; aI[3] = tI[2];
      }
      outR[i] = __builtin_convertvector(aR, f16x4);
      outI[i] = __builtin_convertvector(aI, f16x4);
    }
  }
  if constexpr (!FINAL) {
    __syncthreads();
#pragma unroll
    for (int i = 0; i < 8; ++i) {
      const int rr = (wave * 8 + i) * 16 + 4 * q;
      const int nI = rr | (cc << 10);
      const int pS = nI ^ ((((rr >> 9) | ((cc & 3) << 1)) & 7) << 3);
      *(f16x4*)(reP + pS) = outR[i];
      *(f16x4*)(imP + pS) = outI[i];
    }
  }
}

__global__ __launch_bounds__(BLOCK, 4) void qsim_kernel(
    const float* __restrict__ x, const float* __restrict__ qp,
    const float* __restrict__ fcw, const float* __restrict__ fcb,
    float* __restrict__ out) {
  extern __shared__ unsigned char smem[];
  f16* reP = (f16*)smem;                     // [16384]
  f16* imP = reP + 16384;                    // [16384]
  unsigned char* scr = (unsigned char*)(imP + 16384);   // 2048 B multiuse
  f16* Bc = (f16*)scr;
  float* qc = (float*)(scr + 2048);          // [56]
  float* qs = qc + 56;                       // [56]
  float* xc = qs + 56;                       // [14]
  float* xs = xc + 14;                       // [14]

  const int b = blockIdx.x;
  const int tid = threadIdx.x;

  // ---- angles ----
  if (tid < NQ) {
    float sv, cv; sincosf(0.5f * x[b * NQ + tid], &sv, &cv);
    xc[tid] = cv; xs[tid] = sv;
  } else if (tid >= 64 && tid < 64 + NLAYERS * NQ) {
    const int k = tid - 64;
    float sv, cv; sincosf(0.5f * qp[k], &sv, &cv);
    qc[k] = cv; qs[k] = sv;
  }
  __syncthreads();

  // ---- closed-form state at L1-B entry: amp = Flo(b0-4)*Fhi(b5-8)*Psi[b9-13] ----
  float* Flo  = (float*)scr;        // [32]  prod of ry wires 5-9
  float* psi  = Flo + 32;           // [32]  prod of ry wires 0-4
  float* PsiR = psi + 32;           // [32]
  float* PsiI = PsiR + 32;          // [32]
  if (tid < 32) {
    float f = 1.f;
#pragma unroll
    for (int j = 0; j < 5; ++j) f *= ((tid >> j) & 1) ? xs[5 + j] : xc[5 + j];
    Flo[tid] = f;
  } else if (tid < 64) {
    const int k = tid - 32;
    float f = 1.f;
#pragma unroll
    for (int j = 0; j < 5; ++j) f *= ((k >> j) & 1) ? xs[j] : xc[j];
    psi[k] = f;
  }
  __syncthreads();
  if (tid < 32) {   // Psi = U_L1A(qp[0][0..4] + chain) * psi
    const float c0 = qc[0], c1 = qc[1], c2 = qc[2], c3 = qc[3], c4 = qc[4];
    const float s0 = qs[0], s1 = qs[1], s2 = qs[2], s3 = qs[3], s4 = qs[4];
    const int a = finv5(tid);
    float ar = 0.f, ai = 0.f;
    for (int k = 0; k < 32; ++k) {
      const int d = a ^ k;
      float mag = ((d & 1) ? s0 : c0) * ((d & 2) ? s1 : c1);
      mag *= ((d & 4) ? s2 : c2) * ((d & 8) ? s3 : c3);
      mag *= ((d & 16) ? s4 : c4);
      mag *= psi[k];
      const int t = __popc(d) & 3;
      if (t == 0) ar += mag; else if (t == 1) ai -= mag;
      else if (t == 2) ar -= mag; else ai += mag;
    }
    PsiR[tid] = ar; PsiI[tid] = ai;
  }
  __syncthreads();
  {
    float fhi = 1.f;
#pragma unroll
    for (int j = 0; j < 4; ++j) fhi *= ((tid >> j) & 1) ? xs[10 + j] : xc[10 + j];
    const float cr = fhi * PsiR[tid >> 4], ci = fhi * PsiI[tid >> 4];
    const int pconst = ((tid >> 4) & 7) << 3;
#pragma unroll
    for (int kb = 0; kb < 4; ++kb) {
      f16x8 hr, hi;
#pragma unroll
      for (int j = 0; j < 8; ++j) {
        const float F = Flo[8 * kb + j];
        hr[j] = (f16)(F * cr);
        hi[j] = (f16)(F * ci);
      }
      const int pb = (tid * 32 + 8 * kb) ^ pconst;
      *(f16x8*)(reP + pb) = hr;
      *(f16x8*)(imP + pb) = hi;
    }
  }
  __syncthreads();

  // ---- GEMM passes ----
  build32(Bc, qc, qs, 0 * NQ + 5, tid);  __syncthreads();
  pass32<true>(reP, imP, Bc, tid);       __syncthreads();
  buildC(Bc, qc, qs, 0 * NQ + 10, tid);  __syncthreads();
  passC<false>(reP, imP, Bc, tid, nullptr); __syncthreads();
#pragma unroll
  for (int l = 1; l < 3; ++l) {
    build32(Bc, qc, qs, l * NQ + 0, tid);  __syncthreads();
    pass32<false>(reP, imP, Bc, tid);      __syncthreads();
    build32(Bc, qc, qs, l * NQ + 5, tid);  __syncthreads();
    pass32<true>(reP, imP, Bc, tid);       __syncthreads();
    buildC(Bc, qc, qs, l * NQ + 10, tid);  __syncthreads();
    passC<false>(reP, imP, Bc, tid, nullptr); __syncthreads();
  }
  build32(Bc, qc, qs, 3 * NQ + 0, tid);  __syncthreads();
  pass32<false>(reP, imP, Bc, tid);      __syncthreads();
  build32(Bc, qc, qs, 3 * NQ + 5, tid);  __syncthreads();
  pass32<true>(reP, imP, Bc, tid);       __syncthreads();
  buildC(Bc, qc, qs, 3 * NQ + 10, tid);  __syncthreads();

  float zloc[NQ];
#pragma unroll
  for (int w = 0; w < NQ; ++w) zloc[w] = 0.f;
  passC<true>(reP, imP, Bc, tid, zloc);
  __syncthreads();

  // ---- reduce + linear head (zpart aliases scr) ----
  float* zpart = (float*)scr;        // [8*14]
  float* zbuf  = zpart + 112;        // [14]
#pragma unroll
  for (int w = 0; w < NQ; ++w) {
#pragma unroll
    for (int off = 32; off > 0; off >>= 1)
      zloc[w] += __shfl_down(zloc[w], off, 64);
  }
  const int wave = tid >> 6, lane = tid & 63;
  if (lane == 0) {
#pragma unroll
    for (int w = 0; w < NQ; ++w) zpart[wave * NQ + w] = zloc[w];
  }
  __syncthreads();
  if (tid < NQ) {
    float a = 0.f;
#pragma unroll
    for (int v = 0; v < 8; ++v) a += zpart[v * NQ + tid];
    zbuf[tid] = a;
  }
  __syncthreads();
  if (tid < NCLASSES) {
    float acc = fcb[tid];
#pragma unroll
    for (int w = 0; w < NQ; ++w) acc = fmaf(zbuf[w], fcw[tid * NQ + w], acc);
    out[b * NCLASSES + tid] = acc;
  }
}

extern "C" void kernel_launch(void* const* d_in, const int* in_sizes, int n_in,
                              void* d_out, int out_size, void* d_ws, size_t ws_size,
                              hipStream_t stream) {
  const float* x   = (const float*)d_in[0];
  const float* qp  = (const float*)d_in[1];
  const float* fcw = (const float*)d_in[2];
  const float* fcb = (const float*)d_in[3];
  float* out = (float*)d_out;
  const int B = in_sizes[0] / NQ;

  const size_t shmem = 65536 + 2048 + 448 + 112;   // 68144 B
  (void)hipFuncSetAttribute((const void*)qsim_kernel,
                            hipFuncAttributeMaxDynamicSharedMemorySize, (int)shmem);
  qsim_kernel<<<B, BLOCK, shmem, stream>>>(x, qp, fcw, fcb, out);
}

// Round 7
// 141.498 us; speedup vs baseline: 1.2198x; 1.0326x over previous
//
#include <hip/hip_runtime.h>
#include <hip/hip_fp16.h>
#include <math.h>

// 14-qubit batched statevector sim, MFMA engine (R6-verified logic), R7:
// bank-exact LDS layouts. Layout is per producer/consumer pair:
//   F32 (init/A-store/C-store -> A-read/B-read):
//     phys = t*512 + ((128*(k>>3) + 8*mlow + (k&7)) ^ swz(t)),
//     t = e>>9, mlow = (e>>5)&15, k = e&31, swz(t) = ((t^(t>>3))&7)<<3.
//   F_C (B-store -> C-read):
//     phys = tC*256 + ((128*((e>>3)&1) + 8*((e>>4)&15) + (e&7)) ^ swz(tC)), tC = e>>8.
//   B-planes octet-major: physB(n,k) = 256*(k>>3) + 8*n + (k&7).
// All wave reads are conflict-free (lane-octets tile 32 banks); stores are
// 4-way b64 (~1.58x, writes are the minority of traffic). R6's swizzle keyed
// on per-instruction constants -> 1.24e7 conflict cycles; this keys on the
// lane-varying index.
// Also: double-buffered B-planes, next pass's U built before the mid-barrier
// (removes ~10 barriers); -bi precomputed once per B-frag instead of -Ai per
// A-read. All logical e-index math identical to R6 (verified).
// LDS: 65536 state + 2*2048 planes + 560 angles = 70192 B (model: <=73728
// still allocates 72KB -> 2 blocks/CU; falsifiable via OccupancyPercent).

#define NQ 14
#define NLAYERS 4
#define NCLASSES 10
#define BLOCK 512

typedef _Float16 f16;
typedef _Float16 f16x8 __attribute__((ext_vector_type(8)));
typedef _Float16 f16x4 __attribute__((ext_vector_type(4)));
typedef float f32x4 __attribute__((ext_vector_type(4)));
typedef unsigned int u32;
typedef u32 u32x4 __attribute__((ext_vector_type(4)));

__device__ __forceinline__ f32x4 mf(f16x8 a, f16x8 b, f32x4 c) {
  return __builtin_amdgcn_mfma_f32_16x16x32_f16(a, b, c, 0, 0, 0);
}
__device__ __forceinline__ int swz(int t) { return ((t ^ (t >> 3)) & 7) << 3; }

__device__ __forceinline__ int finv5(int n) {
  n ^= ((n >> 3) & 1) << 4;
  n ^= ((n >> 2) & 1) << 3;
  n ^= ((n >> 1) & 1) << 2;
  n ^= (n & 1) << 1;
  return n;
}
__device__ __forceinline__ int finv3(int n) {
  n ^= ((n >> 2) & 1) << 3;
  n ^= ((n >> 1) & 1) << 2;
  n ^= (n & 1) << 1;
  return n;
}

// element j is REAL iff parity(j)==s; s = topbit(n) ^ parity(8q).
__device__ __forceinline__ void splitB(f16x8 b, int s, f16x8& br, f16x8& bi) {
  u32x4 u = __builtin_bit_cast(u32x4, b);
  const u32 m0 = s ? 0xFFFF0000u : 0x0000FFFFu;
  const u32 m1 = s ? 0x0000FFFFu : 0xFFFF0000u;
  u32x4 r;
  r[0] = u[0] & m0; r[1] = u[1] & m1; r[2] = u[2] & m1; r[3] = u[3] & m0;
  u32x4 ii;
  ii[0] = u[0] ^ r[0]; ii[1] = u[1] ^ r[1]; ii[2] = u[2] ^ r[2]; ii[3] = u[3] ^ r[3];
  br = __builtin_bit_cast(f16x8, r);
  bi = __builtin_bit_cast(f16x8, ii);
}

// 32x32 U-plane (RX on bits0-4 + 4-CNOT chain), octet-major storage.
__device__ __forceinline__ void build32(f16* Bc, const float* qc, const float* qs,
                                        int base, int tid) {
  const float c0 = qc[base], c1 = qc[base+1], c2 = qc[base+2], c3 = qc[base+3], c4 = qc[base+4];
  const float s0 = qs[base], s1 = qs[base+1], s2 = qs[base+2], s3 = qs[base+3], s4 = qs[base+4];
#pragma unroll
  for (int e = tid; e < 1024; e += BLOCK) {
    const int n = e >> 5, k = e & 31;
    const int d = finv5(n) ^ k;
    float mag = ((d & 1) ? s0 : c0) * ((d & 2) ? s1 : c1);
    mag *= ((d & 4) ? s2 : c2) * ((d & 8) ? s3 : c3);
    mag *= ((d & 16) ? s4 : c4);
    const int t = __popc(d) & 3;
    Bc[256 * (k >> 3) + 8 * n + (k & 7)] = (f16)((t == 1 || t == 2) ? -mag : mag);
  }
}
// 16-col C-plane (RX bits0-3 + 3-chain), k>=16 rows zero, octet-major.
__device__ __forceinline__ void buildC(f16* Bc, const float* qc, const float* qs,
                                       int base, int tid) {
  const float c0 = qc[base], c1 = qc[base+1], c2 = qc[base+2], c3 = qc[base+3];
  const float s0 = qs[base], s1 = qs[base+1], s2 = qs[base+2], s3 = qs[base+3];
  if (tid < 512) {
    const int n = tid >> 5, k = tid & 31;
    float v = 0.f;
    if (k < 16) {
      const int d = finv3(n) ^ k;
      float mag = ((d & 1) ? s0 : c0) * ((d & 2) ? s1 : c1);
      mag *= ((d & 4) ? s2 : c2) * ((d & 8) ? s3 : c3);
      const int t = __popc(d) & 3;
      v = (t == 1 || t == 2) ? -mag : mag;
    }
    Bc[256 * (k >> 3) + 8 * n + (k & 7)] = (f16)v;
  }
}

// 5-wire GEMM pass. STORE_C: store into F_C (B-phase) else F32 (A-phase).
// BUILD: 0 none, 1 build32, 2 buildC -- into BcW before the mid-barrier.
template<bool CTRL, bool STORE_C, int BUILD>
__device__ __forceinline__ void pass32(f16* __restrict__ reP, f16* __restrict__ imP,
                                       const f16* __restrict__ BcR, f16* __restrict__ BcW,
                                       const float* __restrict__ qc,
                                       const float* __restrict__ qs, int bbase, int tid) {
  const int lane = tid & 63, wave = tid >> 6;
  const int q = lane >> 4, cc = lane & 15;
  int n0 = cc, n1 = cc | 16;
  if (CTRL && wave >= 4) { n0 ^= 31; n1 ^= 31; }
  const int pq = (0x6 >> q) & 1;
  f16x8 br0, bi0, br1, bi1;
  {
    const f16x8 b0 = *(const f16x8*)(BcR + 256 * q + 8 * n0);
    const f16x8 b1 = *(const f16x8*)(BcR + 256 * q + 8 * n1);
    splitB(b0, ((n0 >> 4) ^ pq) & 1, br0, bi0);
    splitB(b1, ((n1 >> 4) ^ pq) & 1, br1, bi1);
  }
  const f16x8 nbi0 = -bi0, nbi1 = -bi1;
  f16x4 outR[8], outI[8];
#pragma unroll
  for (int i = 0; i < 4; ++i) {
    const int mt = wave * 4 + i;
    const int pA = mt * 512 + ((128 * q + 8 * cc) ^ swz(mt));
    const f16x8 Ar = *(const f16x8*)(reP + pA);
    const f16x8 Ai = *(const f16x8*)(imP + pA);
    {
      f32x4 aR = {0.f,0.f,0.f,0.f}, aI = {0.f,0.f,0.f,0.f};
      aR = mf(Ar, br0, aR); aR = mf(Ai, nbi0, aR);
      aI = mf(Ar, bi0, aI); aI = mf(Ai, br0, aI);
      outR[i * 2 + 0] = __builtin_convertvector(aR, f16x4);
      outI[i * 2 + 0] = __builtin_convertvector(aI, f16x4);
    }
    {
      f32x4 aR = {0.f,0.f,0.f,0.f}, aI = {0.f,0.f,0.f,0.f};
      aR = mf(Ar, br1, aR); aR = mf(Ai, nbi1, aR);
      aI = mf(Ar, bi1, aI); aI = mf(Ai, br1, aI);
      outR[i * 2 + 1] = __builtin_convertvector(aR, f16x4);
      outI[i * 2 + 1] = __builtin_convertvector(aI, f16x4);
    }
  }
  if constexpr (BUILD == 1) build32(BcW, qc, qs, bbase, tid);
  else if constexpr (BUILD == 2) buildC(BcW, qc, qs, bbase, tid);
  __syncthreads();   // all reads done before in-place permuted writes
#pragma unroll
  for (int i = 0; i < 4; ++i) {
    const int mt = wave * 4 + i;
#pragma unroll
    for (int nt = 0; nt < 2; ++nt) {
      const int n5 = nt * 16 + cc;
      int pS;
      if constexpr (STORE_C) {
        const int tC = (mt >> 4) + 2 * n5;
        pS = tC * 256 + ((128 * (q >> 1) + 8 * (mt & 15) + 4 * (q & 1)) ^ swz(tC));
      } else {
        pS = n5 * 512 + ((128 * (2 * (mt & 1) + (q >> 1)) + 8 * (mt >> 1) + 4 * (q & 1)) ^ swz(n5));
      }
      *(f16x4*)(reP + pS) = outR[i * 2 + nt];
      *(f16x4*)(imP + pS) = outI[i * 2 + nt];
    }
  }
}

// 4-wire pass C (K padded to 32). Ext-ctrl (9,10) always; wrap CNOT(13,0) =
// reg-pair swap at store / p-swap at readout (ctrl = cc bit3).
template<bool FINAL, int BUILD>
__device__ __forceinline__ void passC(f16* __restrict__ reP, f16* __restrict__ imP,
                                      const f16* __restrict__ BcR, f16* __restrict__ BcW,
                                      const float* __restrict__ qc,
                                      const float* __restrict__ qs, int bbase, int tid,
                                      float* __restrict__ zloc) {
  const int lane = tid & 63, wave = tid >> 6;
  const int q = lane >> 4, cc = lane & 15;
  int n0 = cc;
  if (wave >= 4) n0 ^= 15;
  const int pq = (0x6 >> q) & 1;
  f16x8 br, bi;
  {
    const f16x8 b = *(const f16x8*)(BcR + 256 * q + 8 * n0);
    splitB(b, ((n0 >> 3) ^ pq) & 1, br, bi);
  }
  const f16x8 nbi = -bi;
  f16x4 outR[8], outI[8];
#pragma unroll
  for (int i = 0; i < 8; ++i) {
    const int mtC = wave * 8 + i;
    const int pA = mtC * 256 + ((128 * (q & 1) + 8 * cc) ^ swz(mtC));
    const f16x8 Ar = *(const f16x8*)(reP + pA);
    const f16x8 Ai = *(const f16x8*)(imP + pA);
    f32x4 aR = {0.f,0.f,0.f,0.f}, aI = {0.f,0.f,0.f,0.f};
    aR = mf(Ar, br, aR); aR = mf(Ai, nbi, aR);
    aI = mf(Ar, bi, aI); aI = mf(Ai, br, aI);
    if constexpr (FINAL) {
      float p0 = aR[0]*aR[0] + aI[0]*aI[0];
      float p1 = aR[1]*aR[1] + aI[1]*aI[1];
      float p2 = aR[2]*aR[2] + aI[2]*aI[2];
      float p3 = aR[3]*aR[3] + aI[3]*aI[3];
      if (cc & 8) { float t = p0; p0 = p1; p1 = t; t = p2; p2 = p3; p3 = t; }
      const float ps = p0 + p1 + p2 + p3;
      zloc[0] += (p0 - p1) + (p2 - p3);
      zloc[1] += (p0 + p1) - (p2 + p3);
      zloc[2] += (q & 1) ? -ps : ps;
      zloc[3] += (q & 2) ? -ps : ps;
#pragma unroll
      for (int w = 0; w < 6; ++w) zloc[4 + w] += ((mtC >> w) & 1) ? -ps : ps;
#pragma unroll
      for (int w = 0; w < 4; ++w) zloc[10 + w] += ((cc >> w) & 1) ? -ps : ps;
    } else {
      if (cc & 8) {
        f32x4 tR = aR, tI = aI;
        aR[0] = tR[1]; aR[1] = tR[0]; aR[2] = tR[3]; aR[3] = tR[2];
        aI[0] = tI[1]; aI[1] = tI[0]; aI[2] = tI[3]; aI[3] = tI[2];
      }
      outR[i] = __builtin_convertvector(aR, f16x4);
      outI[i] = __builtin_convertvector(aI, f16x4);
    }
  }
  if constexpr (BUILD == 1) build32(BcW, qc, qs, bbase, tid);
  if constexpr (!FINAL) {
    __syncthreads();
#pragma unroll
    for (int i = 0; i < 8; ++i) {
      const int mtC = wave * 8 + i;
      const int tP = 2 * cc + (mtC >> 5);
      const int pS = tP * 512 +
          ((128 * (2 * (mtC & 1) + (q >> 1)) + 8 * ((mtC >> 1) & 15) + 4 * (q & 1)) ^ swz(tP));
      *(f16x4*)(reP + pS) = outR[i];
      *(f16x4*)(imP + pS) = outI[i];
    }
  }
}

__global__ __launch_bounds__(BLOCK, 4) void qsim_kernel(
    const float* __restrict__ x, const float* __restrict__ qp,
    const float* __restrict__ fcw, const float* __restrict__ fcb,
    float* __restrict__ out) {
  extern __shared__ unsigned char smem[];
  f16* reP = (f16*)smem;                    // [16384]
  f16* imP = reP + 16384;                   // [16384]
  f16* Bc0 = imP + 16384;                   // [1024]
  f16* Bc1 = Bc0 + 1024;                    // [1024]
  float* qc = (float*)(Bc1 + 1024);         // [56]
  float* qs = qc + 56;                      // [56]
  float* xc = qs + 56;                      // [14]
  float* xs = xc + 14;                      // [14]

  const int b = blockIdx.x;
  const int tid = threadIdx.x;

  // ---- angles ----
  if (tid < NQ) {
    float sv, cv; sincosf(0.5f * x[b * NQ + tid], &sv, &cv);
    xc[tid] = cv; xs[tid] = sv;
  } else if (tid >= 64 && tid < 64 + NLAYERS * NQ) {
    const int k = tid - 64;
    float sv, cv; sincosf(0.5f * qp[k], &sv, &cv);
    qc[k] = cv; qs[k] = sv;
  }
  __syncthreads();

  // ---- initial U(L1-B) build + closed-form scratch (scratch aliases Bc1) ----
  float* Flo  = (float*)Bc1;        // [32]
  float* psi  = Flo + 32;           // [32]
  float* PsiR = psi + 32;           // [32]
  float* PsiI = PsiR + 32;          // [32]
  build32(Bc0, qc, qs, 0 * NQ + 5, tid);
  if (tid < 32) {
    float f = 1.f;
#pragma unroll
    for (int j = 0; j < 5; ++j) f *= ((tid >> j) & 1) ? xs[5 + j] : xc[5 + j];
    Flo[tid] = f;
  } else if (tid < 64) {
    const int k = tid - 32;
    float f = 1.f;
#pragma unroll
    for (int j = 0; j < 5; ++j) f *= ((k >> j) & 1) ? xs[j] : xc[j];
    psi[k] = f;
  }
  __syncthreads();
  if (tid < 32) {   // Psi = U_L1A * psi
    const float c0 = qc[0], c1 = qc[1], c2 = qc[2], c3 = qc[3], c4 = qc[4];
    const float s0 = qs[0], s1 = qs[1], s2 = qs[2], s3 = qs[3], s4 = qs[4];
    const int a = finv5(tid);
    float ar = 0.f, ai = 0.f;
    for (int k = 0; k < 32; ++k) {
      const int d = a ^ k;
      float mag = ((d & 1) ? s0 : c0) * ((d & 2) ? s1 : c1);
      mag *= ((d & 4) ? s2 : c2) * ((d & 8) ? s3 : c3);
      mag *= ((d & 16) ? s4 : c4);
      mag *= psi[k];
      const int t = __popc(d) & 3;
      if (t == 0) ar += mag; else if (t == 1) ai -= mag;
      else if (t == 2) ar -= mag; else ai += mag;
    }
    PsiR[tid] = ar; PsiI[tid] = ai;
  }
  __syncthreads();
  {  // state at L1-B entry: amp(e = tid*32 + k) -> F32 layout
    float fhi = 1.f;
#pragma unroll
    for (int j = 0; j < 4; ++j) fhi *= ((tid >> j) & 1) ? xs[10 + j] : xc[10 + j];
    const float cr = fhi * PsiR[tid >> 4], ci = fhi * PsiI[tid >> 4];
    const int t = tid >> 4;
    const int sz = swz(t);
#pragma unroll
    for (int kb = 0; kb < 4; ++kb) {
      f16x8 hr, hi;
#pragma unroll
      for (int j = 0; j < 8; ++j) {
        const float F = Flo[8 * kb + j];
        hr[j] = (f16)(F * cr);
        hi[j] = (f16)(F * ci);
      }
      const int pb = t * 512 + ((128 * kb + 8 * (tid & 15)) ^ sz);
      *(f16x8*)(reP + pb) = hr;
      *(f16x8*)(imP + pb) = hi;
    }
  }
  __syncthreads();

  // ---- 11 GEMM passes, B-planes double-buffered, builds folded in ----
  pass32<true,  true,  2>(reP, imP, Bc0, Bc1, qc, qs, 0*NQ+10, tid); __syncthreads(); // L1-B
  passC <false, 1>(reP, imP, Bc1, Bc0, qc, qs, 1*NQ+0,  tid, nullptr); __syncthreads(); // L1-C
  pass32<false, false, 1>(reP, imP, Bc0, Bc1, qc, qs, 1*NQ+5,  tid); __syncthreads(); // L2-A
  pass32<true,  true,  2>(reP, imP, Bc1, Bc0, qc, qs, 1*NQ+10, tid); __syncthreads(); // L2-B
  passC <false, 1>(reP, imP, Bc0, Bc1, qc, qs, 2*NQ+0,  tid, nullptr); __syncthreads(); // L2-C
  pass32<false, false, 1>(reP, imP, Bc1, Bc0, qc, qs, 2*NQ+5,  tid); __syncthreads(); // L3-A
  pass32<true,  true,  2>(reP, imP, Bc0, Bc1, qc, qs, 2*NQ+10, tid); __syncthreads(); // L3-B
  passC <false, 1>(reP, imP, Bc1, Bc0, qc, qs, 3*NQ+0,  tid, nullptr); __syncthreads(); // L3-C
  pass32<false, false, 1>(reP, imP, Bc0, Bc1, qc, qs, 3*NQ+5,  tid); __syncthreads(); // L4-A
  pass32<true,  true,  2>(reP, imP, Bc1, Bc0, qc, qs, 3*NQ+10, tid); __syncthreads(); // L4-B

  float zloc[NQ];
#pragma unroll
  for (int w = 0; w < NQ; ++w) zloc[w] = 0.f;
  passC<true, 0>(reP, imP, Bc0, Bc1, qc, qs, 0, tid, zloc);   // L4-C fused readout
  __syncthreads();

  // ---- reduce + linear head (zpart aliases Bc0) ----
  float* zpart = (float*)Bc0;        // [8*14]
  float* zbuf  = zpart + 112;        // [14]
#pragma unroll
  for (int w = 0; w < NQ; ++w) {
#pragma unroll
    for (int off = 32; off > 0; off >>= 1)
      zloc[w] += __shfl_down(zloc[w], off, 64);
  }
  const int wave = tid >> 6, lane = tid & 63;
  if (lane == 0) {
#pragma unroll
    for (int w = 0; w < NQ; ++w) zpart[wave * NQ + w] = zloc[w];
  }
  __syncthreads();
  if (tid < NQ) {
    float a = 0.f;
#pragma unroll
    for (int v = 0; v < 8; ++v) a += zpart[v * NQ + tid];
    zbuf[tid] = a;
  }
  __syncthreads();
  if (tid < NCLASSES) {
    float acc = fcb[tid];
#pragma unroll
    for (int w = 0; w < NQ; ++w) acc = fmaf(zbuf[w], fcw[tid * NQ + w], acc);
    out[b * NCLASSES + tid] = acc;
  }
}

extern "C" void kernel_launch(void* const* d_in, const int* in_sizes, int n_in,
                              void* d_out, int out_size, void* d_ws, size_t ws_size,
                              hipStream_t stream) {
  const float* x   = (const float*)d_in[0];
  const float* qp  = (const float*)d_in[1];
  const float* fcw = (const float*)d_in[2];
  const float* fcb = (const float*)d_in[3];
  float* out = (float*)d_out;
  const int B = in_sizes[0] / NQ;

  const size_t shmem = (size_t)(2 * 16384 + 2 * 1024) * sizeof(f16)
                     + (size_t)(56 + 56 + 14 + 14) * sizeof(float);   // 70192 B
  (void)hipFuncSetAttribute((const void*)qsim_kernel,
                            hipFuncAttributeMaxDynamicSharedMemorySize, (int)shmem);
  qsim_kernel<<<B, BLOCK, shmem, stream>>>(x, qp, fcw, fcb, out);
}

// Round 8
// 140.170 us; speedup vs baseline: 1.2314x; 1.0095x over previous
//
#include <hip/hip_runtime.h>
#include <hip/hip_fp16.h>
#include <math.h>

// 14-qubit batched statevector sim, MFMA engine. R8 = R6 pressure structure
// (builds unfolded, per-i nAi negation, single Bc buffer -> no spill; R6
// measured VGPR=64 with zero scratch traffic) + R7 bank-exact LDS layouts
// (conflicts 1.24e7 -> 6.1e6, reads conflict-free; R7's folded builds caused
// a 54 MB/dispatch scratch spill under the 64-VGPR cap -- reverted).
//
// Layouts (per producer/consumer pair):
//   F32 (init/A-store/C-store -> A-read/B-read):
//     phys = t*512 + ((128*(k>>3) + 8*mlow + (k&7)) ^ swz(t)),
//     t = e>>9, mlow = (e>>5)&15, k = e&31, swz(t) = ((t^(t>>3))&7)<<3.
//   F_C (B-store -> C-read):
//     phys = tC*256 + ((128*((e>>3)&1) + 8*((e>>4)&15) + (e&7)) ^ swz(tC)).
//   B-planes octet-major: physB(n,k) = 256*(k>>3) + 8*n + (k&7).
// All wave reads conflict-free; stores 4-way b64 (~1.58x, minority traffic).
//
// Circuit mapping (R6-verified): each pass S' = S * U^T as complex GEMM via
// v_mfma_f32_16x16x32_f16; U entries pure-real/pure-imag -> one signed plane
// + checkerboard split (s = topbit(n) ^ parity(8q)); index rotation per pass;
// ext-ctrl CNOT = B-address flip n^31/n^15; wrap CNOT(13,0) deferred; embed +
// L1-A closed-form rank-1 init; readout fused into last pass.
// LDS: 65536 state + 2048 Bc + 560 angles = 68144 B (known 2 blocks/CU).

#define NQ 14
#define NLAYERS 4
#define NCLASSES 10
#define BLOCK 512

typedef _Float16 f16;
typedef _Float16 f16x8 __attribute__((ext_vector_type(8)));
typedef _Float16 f16x4 __attribute__((ext_vector_type(4)));
typedef float f32x4 __attribute__((ext_vector_type(4)));
typedef unsigned int u32;
typedef u32 u32x4 __attribute__((ext_vector_type(4)));

__device__ __forceinline__ f32x4 mf(f16x8 a, f16x8 b, f32x4 c) {
  return __builtin_amdgcn_mfma_f32_16x16x32_f16(a, b, c, 0, 0, 0);
}
__device__ __forceinline__ int swz(int t) { return ((t ^ (t >> 3)) & 7) << 3; }

__device__ __forceinline__ int finv5(int n) {
  n ^= ((n >> 3) & 1) << 4;
  n ^= ((n >> 2) & 1) << 3;
  n ^= ((n >> 1) & 1) << 2;
  n ^= (n & 1) << 1;
  return n;
}
__device__ __forceinline__ int finv3(int n) {
  n ^= ((n >> 2) & 1) << 3;
  n ^= ((n >> 1) & 1) << 2;
  n ^= (n & 1) << 1;
  return n;
}

// element j is REAL iff parity(j)==s; s = topbit(n) ^ parity(8q).
__device__ __forceinline__ void splitB(f16x8 b, int s, f16x8& br, f16x8& bi) {
  u32x4 u = __builtin_bit_cast(u32x4, b);
  const u32 m0 = s ? 0xFFFF0000u : 0x0000FFFFu;
  const u32 m1 = s ? 0x0000FFFFu : 0xFFFF0000u;
  u32x4 r;
  r[0] = u[0] & m0; r[1] = u[1] & m1; r[2] = u[2] & m1; r[3] = u[3] & m0;
  u32x4 ii;
  ii[0] = u[0] ^ r[0]; ii[1] = u[1] ^ r[1]; ii[2] = u[2] ^ r[2]; ii[3] = u[3] ^ r[3];
  br = __builtin_bit_cast(f16x8, r);
  bi = __builtin_bit_cast(f16x8, ii);
}

// 32x32 U-plane (RX on bits0-4 + 4-CNOT chain), octet-major storage.
__device__ __forceinline__ void build32(f16* Bc, const float* qc, const float* qs,
                                        int base, int tid) {
  const float c0 = qc[base], c1 = qc[base+1], c2 = qc[base+2], c3 = qc[base+3], c4 = qc[base+4];
  const float s0 = qs[base], s1 = qs[base+1], s2 = qs[base+2], s3 = qs[base+3], s4 = qs[base+4];
#pragma unroll
  for (int e = tid; e < 1024; e += BLOCK) {
    const int n = e >> 5, k = e & 31;
    const int d = finv5(n) ^ k;
    float mag = ((d & 1) ? s0 : c0) * ((d & 2) ? s1 : c1);
    mag *= ((d & 4) ? s2 : c2) * ((d & 8) ? s3 : c3);
    mag *= ((d & 16) ? s4 : c4);
    const int t = __popc(d) & 3;
    Bc[256 * (k >> 3) + 8 * n + (k & 7)] = (f16)((t == 1 || t == 2) ? -mag : mag);
  }
}
// 16-col C-plane (RX bits0-3 + 3-chain), k>=16 rows zero, octet-major.
__device__ __forceinline__ void buildC(f16* Bc, const float* qc, const float* qs,
                                       int base, int tid) {
  const float c0 = qc[base], c1 = qc[base+1], c2 = qc[base+2], c3 = qc[base+3];
  const float s0 = qs[base], s1 = qs[base+1], s2 = qs[base+2], s3 = qs[base+3];
  if (tid < 512) {
    const int n = tid >> 5, k = tid & 31;
    float v = 0.f;
    if (k < 16) {
      const int d = finv3(n) ^ k;
      float mag = ((d & 1) ? s0 : c0) * ((d & 2) ? s1 : c1);
      mag *= ((d & 4) ? s2 : c2) * ((d & 8) ? s3 : c3);
      const int t = __popc(d) & 3;
      v = (t == 1 || t == 2) ? -mag : mag;
    }
    Bc[256 * (k >> 3) + 8 * n + (k & 7)] = (f16)v;
  }
}

// 5-wire GEMM pass. STORE_C: store into F_C (B-phase) else F32 (A-phase).
template<bool CTRL, bool STORE_C>
__device__ __forceinline__ void pass32(f16* __restrict__ reP, f16* __restrict__ imP,
                                       const f16* __restrict__ BcR, int tid) {
  const int lane = tid & 63, wave = tid >> 6;
  const int q = lane >> 4, cc = lane & 15;
  int n0 = cc, n1 = cc | 16;
  if (CTRL && wave >= 4) { n0 ^= 31; n1 ^= 31; }
  const int pq = (0x6 >> q) & 1;
  f16x8 br0, bi0, br1, bi1;
  {
    const f16x8 b0 = *(const f16x8*)(BcR + 256 * q + 8 * n0);
    const f16x8 b1 = *(const f16x8*)(BcR + 256 * q + 8 * n1);
    splitB(b0, ((n0 >> 4) ^ pq) & 1, br0, bi0);
    splitB(b1, ((n1 >> 4) ^ pq) & 1, br1, bi1);
  }
  f16x4 outR[8], outI[8];
#pragma unroll
  for (int i = 0; i < 4; ++i) {
    const int mt = wave * 4 + i;
    const int pA = mt * 512 + ((128 * q + 8 * cc) ^ swz(mt));
    const f16x8 Ar = *(const f16x8*)(reP + pA);
    const f16x8 Ai = *(const f16x8*)(imP + pA);
    const f16x8 nAi = -Ai;
    {
      f32x4 aR = {0.f,0.f,0.f,0.f}, aI = {0.f,0.f,0.f,0.f};
      aR = mf(Ar, br0, aR); aR = mf(nAi, bi0, aR);
      aI = mf(Ar, bi0, aI); aI = mf(Ai, br0, aI);
      outR[i * 2 + 0] = __builtin_convertvector(aR, f16x4);
      outI[i * 2 + 0] = __builtin_convertvector(aI, f16x4);
    }
    {
      f32x4 aR = {0.f,0.f,0.f,0.f}, aI = {0.f,0.f,0.f,0.f};
      aR = mf(Ar, br1, aR); aR = mf(nAi, bi1, aR);
      aI = mf(Ar, bi1, aI); aI = mf(Ai, br1, aI);
      outR[i * 2 + 1] = __builtin_convertvector(aR, f16x4);
      outI[i * 2 + 1] = __builtin_convertvector(aI, f16x4);
    }
  }
  __syncthreads();   // all reads done before in-place permuted writes
#pragma unroll
  for (int i = 0; i < 4; ++i) {
    const int mt = wave * 4 + i;
#pragma unroll
    for (int nt = 0; nt < 2; ++nt) {
      const int n5 = nt * 16 + cc;
      int pS;
      if constexpr (STORE_C) {
        const int tC = (mt >> 4) + 2 * n5;
        pS = tC * 256 + ((128 * (q >> 1) + 8 * (mt & 15) + 4 * (q & 1)) ^ swz(tC));
      } else {
        pS = n5 * 512 + ((128 * (2 * (mt & 1) + (q >> 1)) + 8 * (mt >> 1) + 4 * (q & 1)) ^ swz(n5));
      }
      *(f16x4*)(reP + pS) = outR[i * 2 + nt];
      *(f16x4*)(imP + pS) = outI[i * 2 + nt];
    }
  }
}

// 4-wire pass C (K padded to 32). Ext-ctrl (9,10) always; wrap CNOT(13,0) =
// reg-pair swap at store / p-swap at readout (ctrl = cc bit3).
template<bool FINAL>
__device__ __forceinline__ void passC(f16* __restrict__ reP, f16* __restrict__ imP,
                                      const f16* __restrict__ BcR, int tid,
                                      float* __restrict__ zloc) {
  const int lane = tid & 63, wave = tid >> 6;
  const int q = lane >> 4, cc = lane & 15;
  int n0 = cc;
  if (wave >= 4) n0 ^= 15;
  const int pq = (0x6 >> q) & 1;
  f16x8 br, bi;
  {
    const f16x8 b = *(const f16x8*)(BcR + 256 * q + 8 * n0);
    splitB(b, ((n0 >> 3) ^ pq) & 1, br, bi);
  }
  f16x4 outR[8], outI[8];
#pragma unroll
  for (int i = 0; i < 8; ++i) {
    const int mtC = wave * 8 + i;
    const int pA = mtC * 256 + ((128 * (q & 1) + 8 * cc) ^ swz(mtC));
    const f16x8 Ar = *(const f16x8*)(reP + pA);
    const f16x8 Ai = *(const f16x8*)(imP + pA);
    const f16x8 nAi = -Ai;
    f32x4 aR = {0.f,0.f,0.f,0.f}, aI = {0.f,0.f,0.f,0.f};
    aR = mf(Ar, br, aR); aR = mf(nAi, bi, aR);
    aI = mf(Ar, bi, aI); aI = mf(Ai, br, aI);
    if constexpr (FINAL) {
      float p0 = aR[0]*aR[0] + aI[0]*aI[0];
      float p1 = aR[1]*aR[1] + aI[1]*aI[1];
      float p2 = aR[2]*aR[2] + aI[2]*aI[2];
      float p3 = aR[3]*aR[3] + aI[3]*aI[3];
      if (cc & 8) { float t = p0; p0 = p1; p1 = t; t = p2; p2 = p3; p3 = t; }
      const float ps = p0 + p1 + p2 + p3;
      zloc[0] += (p0 - p1) + (p2 - p3);
      zloc[1] += (p0 + p1) - (p2 + p3);
      zloc[2] += (q & 1) ? -ps : ps;
      zloc[3] += (q & 2) ? -ps : ps;
#pragma unroll
      for (int w = 0; w < 6; ++w) zloc[4 + w] += ((mtC >> w) & 1) ? -ps : ps;
#pragma unroll
      for (int w = 0; w < 4; ++w) zloc[10 + w] += ((cc >> w) & 1) ? -ps : ps;
    } else {
      if (cc & 8) {
        f32x4 tR = aR, tI = aI;
        aR[0] = tR[1]; aR[1] = tR[0]; aR[2] = tR[3]; aR[3] = tR[2];
        aI[0] = tI[1]; aI[1] = tI[0]; aI[2] = tI[3]; aI[3] = tI[2];
      }
      outR[i] = __builtin_convertvector(aR, f16x4);
      outI[i] = __builtin_convertvector(aI, f16x4);
    }
  }
  if constexpr (!FINAL) {
    __syncthreads();
#pragma unroll
    for (int i = 0; i < 8; ++i) {
      const int mtC = wave * 8 + i;
      const int tP = 2 * cc + (mtC >> 5);
      const int pS = tP * 512 +
          ((128 * (2 * (mtC & 1) + (q >> 1)) + 8 * ((mtC >> 1) & 15) + 4 * (q & 1)) ^ swz(tP));
      *(f16x4*)(reP + pS) = outR[i];
      *(f16x4*)(imP + pS) = outI[i];
    }
  }
}

__global__ __launch_bounds__(BLOCK, 4) void qsim_kernel(
    const float* __restrict__ x, const float* __restrict__ qp,
    const float* __restrict__ fcw, const float* __restrict__ fcb,
    float* __restrict__ out) {
  extern __shared__ unsigned char smem[];
  f16* reP = (f16*)smem;                    // [16384]
  f16* imP = reP + 16384;                   // [16384]
  f16* Bc  = imP + 16384;                   // [1024] (aliased as init scratch)
  float* qc = (float*)(Bc + 1024);          // [56]
  float* qs = qc + 56;                      // [56]
  float* xc = qs + 56;                      // [14]
  float* xs = xc + 14;                      // [14]

  const int b = blockIdx.x;
  const int tid = threadIdx.x;

  // ---- angles ----
  if (tid < NQ) {
    float sv, cv; sincosf(0.5f * x[b * NQ + tid], &sv, &cv);
    xc[tid] = cv; xs[tid] = sv;
  } else if (tid >= 64 && tid < 64 + NLAYERS * NQ) {
    const int k = tid - 64;
    float sv, cv; sincosf(0.5f * qp[k], &sv, &cv);
    qc[k] = cv; qs[k] = sv;
  }
  __syncthreads();

  // ---- closed-form state at L1-B entry (scratch aliases Bc) ----
  float* Flo  = (float*)Bc;         // [32]
  float* psi  = Flo + 32;           // [32]
  float* PsiR = psi + 32;           // [32]
  float* PsiI = PsiR + 32;          // [32]
  if (tid < 32) {
    float f = 1.f;
#pragma unroll
    for (int j = 0; j < 5; ++j) f *= ((tid >> j) & 1) ? xs[5 + j] : xc[5 + j];
    Flo[tid] = f;
  } else if (tid < 64) {
    const int k = tid - 32;
    float f = 1.f;
#pragma unroll
    for (int j = 0; j < 5; ++j) f *= ((k >> j) & 1) ? xs[j] : xc[j];
    psi[k] = f;
  }
  __syncthreads();
  if (tid < 32) {   // Psi = U_L1A * psi
    const float c0 = qc[0], c1 = qc[1], c2 = qc[2], c3 = qc[3], c4 = qc[4];
    const float s0 = qs[0], s1 = qs[1], s2 = qs[2], s3 = qs[3], s4 = qs[4];
    const int a = finv5(tid);
    float ar = 0.f, ai = 0.f;
    for (int k = 0; k < 32; ++k) {
      const int d = a ^ k;
      float mag = ((d & 1) ? s0 : c0) * ((d & 2) ? s1 : c1);
      mag *= ((d & 4) ? s2 : c2) * ((d & 8) ? s3 : c3);
      mag *= ((d & 16) ? s4 : c4);
      mag *= psi[k];
      const int t = __popc(d) & 3;
      if (t == 0) ar += mag; else if (t == 1) ai -= mag;
      else if (t == 2) ar -= mag; else ai += mag;
    }
    PsiR[tid] = ar; PsiI[tid] = ai;
  }
  __syncthreads();
  {  // state at L1-B entry: amp(e = tid*32 + k) -> F32 layout
    float fhi = 1.f;
#pragma unroll
    for (int j = 0; j < 4; ++j) fhi *= ((tid >> j) & 1) ? xs[10 + j] : xc[10 + j];
    const float cr = fhi * PsiR[tid >> 4], ci = fhi * PsiI[tid >> 4];
    const int t = tid >> 4;
    const int sz = swz(t);
    float Fl[32];
#pragma unroll
    for (int j = 0; j < 32; ++j) Fl[j] = Flo[j];
    __syncthreads();   // scratch reads done; Bc free for builds
#pragma unroll
    for (int kb = 0; kb < 4; ++kb) {
      f16x8 hr, hi;
#pragma unroll
      for (int j = 0; j < 8; ++j) {
        const float F = Fl[8 * kb + j];
        hr[j] = (f16)(F * cr);
        hi[j] = (f16)(F * ci);
      }
      const int pb = t * 512 + ((128 * kb + 8 * (tid & 15)) ^ sz);
      *(f16x8*)(reP + pb) = hr;
      *(f16x8*)(imP + pb) = hi;
    }
  }
  build32(Bc, qc, qs, 0 * NQ + 5, tid);   // U(L1-B); Bc scratch reads already fenced
  __syncthreads();

  // ---- 11 GEMM passes, builds as separate steps (no folding -> no spill) ----
  pass32<true, true>(reP, imP, Bc, tid);          __syncthreads(); // L1-B
  buildC(Bc, qc, qs, 0 * NQ + 10, tid);           __syncthreads();
  passC<false>(reP, imP, Bc, tid, nullptr);       __syncthreads(); // L1-C
#pragma unroll
  for (int l = 1; l < NLAYERS; ++l) {
    build32(Bc, qc, qs, l * NQ + 0, tid);         __syncthreads();
    pass32<false, false>(reP, imP, Bc, tid);      __syncthreads(); // A
    build32(Bc, qc, qs, l * NQ + 5, tid);         __syncthreads();
    pass32<true, true>(reP, imP, Bc, tid);        __syncthreads(); // B
    buildC(Bc, qc, qs, l * NQ + 10, tid);         __syncthreads();
    if (l < NLAYERS - 1) {
      passC<false>(reP, imP, Bc, tid, nullptr);   __syncthreads(); // C
    }
  }

  float zloc[NQ];
#pragma unroll
  for (int w = 0; w < NQ; ++w) zloc[w] = 0.f;
  passC<true>(reP, imP, Bc, tid, zloc);           // L4-C fused readout
  __syncthreads();

  // ---- reduce + linear head (zpart aliases Bc) ----
  float* zpart = (float*)Bc;         // [8*14]
  float* zbuf  = zpart + 112;        // [14]
#pragma unroll
  for (int w = 0; w < NQ; ++w) {
#pragma unroll
    for (int off = 32; off > 0; off >>= 1)
      zloc[w] += __shfl_down(zloc[w], off, 64);
  }
  const int wave = tid >> 6, lane = tid & 63;
  if (lane == 0) {
#pragma unroll
    for (int w = 0; w < NQ; ++w) zpart[wave * NQ + w] = zloc[w];
  }
  __syncthreads();
  if (tid < NQ) {
    float a = 0.f;
#pragma unroll
    for (int v = 0; v < 8; ++v) a += zpart[v * NQ + tid];
    zbuf[tid] = a;
  }
  __syncthreads();
  if (tid < NCLASSES) {
    float acc = fcb[tid];
#pragma unroll
    for (int w = 0; w < NQ; ++w) acc = fmaf(zbuf[w], fcw[tid * NQ + w], acc);
    out[b * NCLASSES + tid] = acc;
  }
}

extern "C" void kernel_launch(void* const* d_in, const int* in_sizes, int n_in,
                              void* d_out, int out_size, void* d_ws, size_t ws_size,
                              hipStream_t stream) {
  const float* x   = (const float*)d_in[0];
  const float* qp  = (const float*)d_in[1];
  const float* fcw = (const float*)d_in[2];
  const float* fcb = (const float*)d_in[3];
  float* out = (float*)d_out;
  const int B = in_sizes[0] / NQ;

  const size_t shmem = (size_t)(2 * 16384 + 1024) * sizeof(f16)
                     + (size_t)(56 + 56 + 14 + 14) * sizeof(float);   // 68144 B
  (void)hipFuncSetAttribute((const void*)qsim_kernel,
                            hipFuncAttributeMaxDynamicSharedMemorySize, (int)shmem);
  qsim_kernel<<<B, BLOCK, shmem, stream>>>(x, qp, fcw, fcb, out);
}